// Round 1
// baseline (11.444 us; speedup 1.0000x reference)
//
#include <hip/hip_runtime.h>

// out[b, q] = prod_{i=0}^{N-1-q} cos(x[b, i])
//
// Derivation: RX(x_i) on |0> gives bit i = 1 with prob sin^2(x_i/2),
// independently per qubit. The CNOT ladder (ctrl i -> tgt i+1, i ascending)
// turns measured bit j into the prefix XOR b_0^...^b_j. Therefore
// <Z_j> = prod_{i<=j} E[(-1)^{b_i}] = prod_{i<=j} cos(x_i), and the
// little-endian label reversal maps output column q to qubit n-1-q.

#define NQ 14
#define BATCH 2048

__global__ void QGate_65481071401635_kernel(const float* __restrict__ x,
                                            float* __restrict__ out) {
    int b = blockIdx.x * blockDim.x + threadIdx.x;
    if (b >= BATCH) return;
    const float* xr = x + b * NQ;
    float* orow = out + b * NQ;
    float p = 1.0f;
#pragma unroll
    for (int i = 0; i < NQ; ++i) {
        p *= cosf(xr[i]);
        orow[NQ - 1 - i] = p;  // out[b, n-1-i] = prefix product through i
    }
}

extern "C" void kernel_launch(void* const* d_in, const int* in_sizes, int n_in,
                              void* d_out, int out_size, void* d_ws, size_t ws_size,
                              hipStream_t stream) {
    const float* x = (const float*)d_in[0];
    float* out = (float*)d_out;
    const int block = 64;
    const int grid = (BATCH + block - 1) / block;  // 32 blocks -> spread over CUs
    QGate_65481071401635_kernel<<<grid, block, 0, stream>>>(x, out);
}

// Round 2
// 9.765 us; speedup vs baseline: 1.1719x; 1.1719x over previous
//
#include <hip/hip_runtime.h>

// out[b, q] = prod_{i=0}^{N-1-q} cos(x[b, i])
//
// Derivation: RX(x_i) on |0> gives bit i = 1 with prob sin^2(x_i/2),
// independently per qubit. The CNOT ladder (ctrl i -> tgt i+1, i ascending)
// turns measured bit j into the prefix XOR b_0^...^b_j. Therefore
// <Z_j> = prod_{i<=j} cos(x_i), and the little-endian label reversal maps
// output column q to qubit n-1-q.
//
// R1: kernel exec is sub-us (not in rocprof top-5); dur_us ~11.4 is
// launch/graph-replay overhead. Swap libm cosf -> hardware __cosf
// (v_cos_f32, ~1e-5 accuracy for |x|<~5, threshold is 2e-2) to shave the
// remaining VALU tail. If dur_us is unchanged, we are at the overhead floor.

#define NQ 14
#define BATCH 2048

__global__ void QGate_65481071401635_kernel(const float* __restrict__ x,
                                            float* __restrict__ out) {
    int b = blockIdx.x * blockDim.x + threadIdx.x;
    if (b >= BATCH) return;
    const float* xr = x + b * NQ;
    float* orow = out + b * NQ;

    float c[NQ];
#pragma unroll
    for (int i = 0; i < NQ; ++i) {
        c[i] = __cosf(xr[i]);  // v_cos_f32 path, independent -> pipelined
    }
    float p = 1.0f;
#pragma unroll
    for (int i = 0; i < NQ; ++i) {
        p *= c[i];
        orow[NQ - 1 - i] = p;  // out[b, n-1-i] = prefix product through i
    }
}

extern "C" void kernel_launch(void* const* d_in, const int* in_sizes, int n_in,
                              void* d_out, int out_size, void* d_ws, size_t ws_size,
                              hipStream_t stream) {
    const float* x = (const float*)d_in[0];
    float* out = (float*)d_out;
    const int block = 64;
    const int grid = (BATCH + block - 1) / block;  // 32 blocks
    QGate_65481071401635_kernel<<<grid, block, 0, stream>>>(x, out);
}